// Round 2
// baseline (221.591 us; speedup 1.0000x reference)
//
#include <hip/hip_runtime.h>
#include <hip/hip_bf16.h>
#include <stdint.h>

#define B_   4
#define SEQ_ 1024
#define DM   1024
#define H_   16
#define HD   64

typedef __bf16 bf16;
typedef __bf16 bf16x8 __attribute__((ext_vector_type(8)));
typedef __bf16 bf16x4v __attribute__((ext_vector_type(4)));
typedef float  f32x4 __attribute__((ext_vector_type(4)));

__device__ __forceinline__ void gl_lds16(const void* g, void* s_uniform) {
    __builtin_amdgcn_global_load_lds(
        (const __attribute__((address_space(1))) uint32_t*)g,
        (__attribute__((address_space(3))) uint32_t*)s_uniform,
        16, 0, 0);
}

// ---------------------------------------------------------------------------
// prep: fp32 -> bf16 casts + T5 relative-position bias table [h][dist]
// ---------------------------------------------------------------------------
__global__ __launch_bounds__(256) void prep_kernel(
    const float* __restrict__ x, const float* __restrict__ Wq,
    const float* __restrict__ Wk, const float* __restrict__ Wv,
    const float* __restrict__ Wo, const float* __restrict__ rel,
    bf16* __restrict__ xb, bf16* __restrict__ wqkvb, bf16* __restrict__ wob,
    float* __restrict__ biasT)
{
    int tid = blockIdx.x * 256 + threadIdx.x;
    int stride = gridDim.x * 256;

    for (int i = tid; i < (B_*SEQ_*DM)/4; i += stride) {
        float4 v = ((const float4*)x)[i];
        bf16x4v o; o[0]=(bf16)v.x; o[1]=(bf16)v.y; o[2]=(bf16)v.z; o[3]=(bf16)v.w;
        ((bf16x4v*)xb)[i] = o;
    }
    for (int i = tid; i < (3*DM*DM)/4; i += stride) {
        int n = i >> 8, k4 = i & 255;
        const float* src = (n < 1024) ? Wq : (n < 2048) ? Wk : Wv;
        float4 v = ((const float4*)(src + (size_t)(n & 1023) * DM))[k4];
        bf16x4v o; o[0]=(bf16)v.x; o[1]=(bf16)v.y; o[2]=(bf16)v.z; o[3]=(bf16)v.w;
        ((bf16x4v*)wqkvb)[i] = o;
    }
    for (int i = tid; i < (DM*DM)/4; i += stride) {
        float4 v = ((const float4*)Wo)[i];
        bf16x4v o; o[0]=(bf16)v.x; o[1]=(bf16)v.y; o[2]=(bf16)v.z; o[3]=(bf16)v.w;
        ((bf16x4v*)wob)[i] = o;
    }
    for (int i = tid; i < H_ * SEQ_; i += stride) {
        int h = i >> 10, dist = i & 1023;
        int bkt;
        if (dist < 16) {
            bkt = dist;
        } else {
            float r = logf((float)dist * (1.0f/16.0f)) / logf(8.0f) * 16.0f;
            int vb = 16 + (int)r;
            bkt = vb > 31 ? 31 : vb;
        }
        biasT[i] = rel[bkt * H_ + h] * 0.125f;
    }
}

// ---------------------------------------------------------------------------
// GEMM C = A @ B^T  (both A and B K-contiguous, bf16, fp32 accumulate)
// 128x128 tile, BK=64, 256 threads (4 waves, 2x2 of 64x64), mfma 16x16x32
// ---------------------------------------------------------------------------
template<int MODE>
__global__ __launch_bounds__(256) void gemm_bt(
    const bf16* __restrict__ A, const bf16* __restrict__ Bm, int K,
    bf16* __restrict__ qb, bf16* __restrict__ kb, bf16* __restrict__ vtb,
    const float* __restrict__ bq, const float* __restrict__ bk,
    const float* __restrict__ bv,
    float* __restrict__ outp, const float* __restrict__ bo, int Nout)
{
    __shared__ __align__(16) bf16 As[128 * 64];
    __shared__ __align__(16) bf16 Bs[128 * 64];

    int t = threadIdx.x;
    int lane = t & 63, w = t >> 6;
    int wr = w >> 1, wc = w & 1;
    int m0 = blockIdx.y * 128, n0 = blockIdx.x * 128;
    int row_l = lane & 15;
    int ksl = (lane >> 4) * 8;

    f32x4 acc[4][4] = {};

    for (int k0 = 0; k0 < K; k0 += 64) {
        #pragma unroll
        for (int i = 0; i < 4; ++i) {
            int e = i * 2048 + t * 8;
            int r = e >> 6, c = e & 63;
            gl_lds16(A  + (long)(m0 + r) * K + k0 + c, &As[i * 2048 + w * 512]);
            gl_lds16(Bm + (long)(n0 + r) * K + k0 + c, &Bs[i * 2048 + w * 512]);
        }
        __syncthreads();
        #pragma unroll
        for (int kk = 0; kk < 2; ++kk) {
            bf16x8 af[4], bfr[4];
            #pragma unroll
            for (int mi = 0; mi < 4; ++mi)
                af[mi] = *(const bf16x8*)&As[(wr*64 + mi*16 + row_l)*64 + kk*32 + ksl];
            #pragma unroll
            for (int ni = 0; ni < 4; ++ni)
                bfr[ni] = *(const bf16x8*)&Bs[(wc*64 + ni*16 + row_l)*64 + kk*32 + ksl];
            #pragma unroll
            for (int mi = 0; mi < 4; ++mi)
                #pragma unroll
                for (int ni = 0; ni < 4; ++ni)
                    acc[mi][ni] = __builtin_amdgcn_mfma_f32_16x16x32_bf16(
                        af[mi], bfr[ni], acc[mi][ni], 0, 0, 0);
        }
        __syncthreads();
    }

    int rbase = (lane >> 4) * 4;
    #pragma unroll
    for (int mi = 0; mi < 4; ++mi) {
        #pragma unroll
        for (int ni = 0; ni < 4; ++ni) {
            #pragma unroll
            for (int g = 0; g < 4; ++g) {
                int m = m0 + wr*64 + mi*16 + rbase + g;
                int n = n0 + wc*64 + ni*16 + (lane & 15);
                float v = acc[mi][ni][g];
                if (MODE == 0) {
                    int which = n >> 10, nn = n & 1023;
                    int h = nn >> 6, d = nn & 63;
                    int b = m >> 10, s = m & 1023;
                    const float* bias = (which == 0) ? bq : (which == 1) ? bk : bv;
                    v += bias[nn];
                    bf16 bv16 = (bf16)v;
                    if (which == 0)
                        qb[((long)(b*H_ + h)*SEQ_ + s)*HD + d] = bv16;
                    else if (which == 1)
                        kb[((long)(b*H_ + h)*SEQ_ + s)*HD + d] = bv16;
                    else
                        vtb[((long)(b*H_ + h)*HD + d)*SEQ_ + s] = bv16;
                } else {
                    outp[(long)m * Nout + n] = v + bo[n];
                }
            }
        }
    }
}

// ---------------------------------------------------------------------------
// Flash attention v2: NO K/V LDS staging (L2-resident), frags direct
// global->VGPR; per-wave padded P buffer; zero barriers in the K-loop.
// ---------------------------------------------------------------------------
#define PSTRIDE 72

__global__ __launch_bounds__(256) void attn_kernel(
    const bf16* __restrict__ Qb, const bf16* __restrict__ Kb,
    const bf16* __restrict__ Vtb, const float* __restrict__ biasT,
    bf16* __restrict__ AO)
{
    __shared__ __align__(16) bf16 Ps[4][16 * PSTRIDE];
    __shared__ float biasS[SEQ_];

    int t = threadIdx.x;
    int lane = t & 63, w = t >> 6;
    int qt = blockIdx.x, bh = blockIdx.y;
    int h = bh & 15, b = bh >> 4;
    int q0 = qt * 64;
    int row_l = lane & 15;
    int ksl = (lane >> 4) * 8;
    int rbase = (lane >> 4) * 4;

    // stage this head's bias row (1024 f32) into LDS, one barrier total
    ((float4*)biasS)[t] = ((const float4*)(biasT + (long)h * SEQ_))[t];
    __syncthreads();

    // Q fragments held in registers for the whole block
    const bf16* Qp = Qb + ((long)bh * SEQ_ + q0 + w * 16) * HD;
    bf16x8 qf0 = *(const bf16x8*)&Qp[row_l * HD + ksl];
    bf16x8 qf1 = *(const bf16x8*)&Qp[row_l * HD + 32 + ksl];

    f32x4 oacc[4] = {};
    float m_run[4], l_run[4];
    int i_row[4];
    #pragma unroll
    for (int g = 0; g < 4; ++g) {
        m_run[g] = -1e30f; l_run[g] = 0.f;
        i_row[g] = q0 + w * 16 + rbase + g;
    }

    const bf16* Kbase = Kb + (long)bh * SEQ_ * HD;
    const bf16* Vbase = Vtb + (long)bh * HD * SEQ_;

    for (int jt = 0; jt <= qt; ++jt) {
        // --- load all K/V fragments for this tile straight from global (L2)
        bf16x8 kfr[4][2], vfr[4][2];
        #pragma unroll
        for (int f = 0; f < 4; ++f) {
            const bf16* kp = Kbase + (long)(jt*64 + f*16 + row_l) * HD + ksl;
            kfr[f][0] = *(const bf16x8*)kp;
            kfr[f][1] = *(const bf16x8*)(kp + 32);
            const bf16* vp = Vbase + (long)(f*16 + row_l) * SEQ_ + jt*64 + ksl;
            vfr[f][0] = *(const bf16x8*)vp;
            vfr[f][1] = *(const bf16x8*)(vp + 32);
        }

        // --- S = Q K^T
        f32x4 sacc[4] = {};
        #pragma unroll
        for (int f = 0; f < 4; ++f) {
            sacc[f] = __builtin_amdgcn_mfma_f32_16x16x32_bf16(qf0, kfr[f][0], sacc[f], 0,0,0);
            sacc[f] = __builtin_amdgcn_mfma_f32_16x16x32_bf16(qf1, kfr[f][1], sacc[f], 0,0,0);
        }

        // --- bias + causal mask
        float s_v[4][4];
        #pragma unroll
        for (int f = 0; f < 4; ++f) {
            int j = jt * 64 + f * 16 + row_l;
            #pragma unroll
            for (int g = 0; g < 4; ++g) {
                int i_ = i_row[g];
                s_v[f][g] = (j <= i_) ? (sacc[f][g] + biasS[i_ - j]) : -1e30f;
            }
        }

        // --- online softmax
        float pv[4][4], sc_a[4];
        #pragma unroll
        for (int g = 0; g < 4; ++g) {
            float mx = fmaxf(fmaxf(s_v[0][g], s_v[1][g]), fmaxf(s_v[2][g], s_v[3][g]));
            #pragma unroll
            for (int off = 1; off < 16; off <<= 1) mx = fmaxf(mx, __shfl_xor(mx, off));
            float mnew = fmaxf(m_run[g], mx);
            float sc = __expf(m_run[g] - mnew);
            float rs = 0.f;
            #pragma unroll
            for (int f = 0; f < 4; ++f) {
                float p = __expf(s_v[f][g] - mnew);
                pv[f][g] = p; rs += p;
            }
            #pragma unroll
            for (int off = 1; off < 16; off <<= 1) rs += __shfl_xor(rs, off);
            l_run[g] = l_run[g] * sc + rs;
            m_run[g] = mnew;
            sc_a[g] = sc;
        }
        #pragma unroll
        for (int db = 0; db < 4; ++db)
            #pragma unroll
            for (int g = 0; g < 4; ++g)
                oacc[db][g] *= sc_a[g];

        // --- P (C-layout) -> per-wave LDS (padded rows) -> A-layout frags
        #pragma unroll
        for (int f = 0; f < 4; ++f)
            #pragma unroll
            for (int g = 0; g < 4; ++g)
                Ps[w][(rbase + g) * PSTRIDE + f * 16 + row_l] = (bf16)pv[f][g];

        bf16x8 pf0 = *(const bf16x8*)&Ps[w][row_l * PSTRIDE + ksl];
        bf16x8 pf1 = *(const bf16x8*)&Ps[w][row_l * PSTRIDE + 32 + ksl];

        // --- O += P V
        #pragma unroll
        for (int db = 0; db < 4; ++db) {
            oacc[db] = __builtin_amdgcn_mfma_f32_16x16x32_bf16(pf0, vfr[db][0], oacc[db], 0,0,0);
            oacc[db] = __builtin_amdgcn_mfma_f32_16x16x32_bf16(pf1, vfr[db][1], oacc[db], 0,0,0);
        }
    }

    // epilogue
    #pragma unroll
    for (int g = 0; g < 4; ++g) {
        float inv = 1.0f / l_run[g];
        long base = ((long)(b * SEQ_ + i_row[g])) * DM + h * HD;
        #pragma unroll
        for (int db = 0; db < 4; ++db)
            AO[base + db * 16 + row_l] = (bf16)(oacc[db][g] * inv);
    }
}

// ---------------------------------------------------------------------------
extern "C" void kernel_launch(void* const* d_in, const int* in_sizes, int n_in,
                              void* d_out, int out_size, void* d_ws, size_t ws_size,
                              hipStream_t stream)
{
    const float* x   = (const float*)d_in[0];
    const float* Wq  = (const float*)d_in[1];
    const float* bq  = (const float*)d_in[2];
    const float* Wk  = (const float*)d_in[3];
    const float* bk  = (const float*)d_in[4];
    const float* Wv  = (const float*)d_in[5];
    const float* bv  = (const float*)d_in[6];
    const float* Wo  = (const float*)d_in[7];
    const float* bo  = (const float*)d_in[8];
    const float* rel = (const float*)d_in[9];
    float* out = (float*)d_out;

    char* ws = (char*)d_ws;
    bf16* xb    = (bf16*)ws;  ws += (size_t)B_*SEQ_*DM * 2;
    bf16* wqkvb = (bf16*)ws;  ws += (size_t)3*DM*DM * 2;
    bf16* wob   = (bf16*)ws;  ws += (size_t)DM*DM * 2;
    float* biasT= (float*)ws; ws += (size_t)H_*SEQ_ * 4;
    bf16* Qb    = (bf16*)ws;  ws += (size_t)B_*H_*SEQ_*HD * 2;
    bf16* Kb2   = (bf16*)ws;  ws += (size_t)B_*H_*SEQ_*HD * 2;
    bf16* Vtb   = (bf16*)ws;  ws += (size_t)B_*H_*SEQ_*HD * 2;
    bf16* AO    = (bf16*)ws;  ws += (size_t)B_*SEQ_*DM * 2;

    prep_kernel<<<2048, 256, 0, stream>>>(x, Wq, Wk, Wv, Wo, rel,
                                          xb, wqkvb, wob, biasT);

    dim3 g1(24, 32);
    gemm_bt<0><<<g1, 256, 0, stream>>>(xb, wqkvb, DM,
                                       Qb, Kb2, Vtb, bq, bk, bv,
                                       nullptr, nullptr, 0);

    dim3 g2(16, 64);
    attn_kernel<<<g2, 256, 0, stream>>>(Qb, Kb2, Vtb, biasT, AO);

    dim3 g3(8, 32);
    gemm_bt<1><<<g3, 256, 0, stream>>>(AO, wob, DM,
                                       nullptr, nullptr, nullptr,
                                       nullptr, nullptr, nullptr,
                                       out, bo, DM);
}

// Round 3
// 152.308 us; speedup vs baseline: 1.4549x; 1.4549x over previous
//
#include <hip/hip_runtime.h>
#include <hip/hip_bf16.h>
#include <stdint.h>

#define B_   4
#define SEQ_ 1024
#define DM   1024
#define H_   16
#define HD   64

typedef __bf16 bf16;
typedef __bf16 bf16x8 __attribute__((ext_vector_type(8)));
typedef __bf16 bf16x4v __attribute__((ext_vector_type(4)));
typedef float  f32x4 __attribute__((ext_vector_type(4)));

__device__ __forceinline__ void gl_lds16(const void* g, void* s_uniform) {
    __builtin_amdgcn_global_load_lds(
        (const __attribute__((address_space(1))) uint32_t*)g,
        (__attribute__((address_space(3))) uint32_t*)s_uniform,
        16, 0, 0);
}

// ---------------------------------------------------------------------------
// prep: fp32 -> bf16 casts + T5 relative-position bias table [h][dist]
// ---------------------------------------------------------------------------
__global__ __launch_bounds__(256) void prep_kernel(
    const float* __restrict__ x, const float* __restrict__ Wq,
    const float* __restrict__ Wk, const float* __restrict__ Wv,
    const float* __restrict__ Wo, const float* __restrict__ rel,
    bf16* __restrict__ xb, bf16* __restrict__ wqkvb, bf16* __restrict__ wob,
    float* __restrict__ biasT)
{
    int tid = blockIdx.x * 256 + threadIdx.x;
    int stride = gridDim.x * 256;

    for (int i = tid; i < (B_*SEQ_*DM)/4; i += stride) {
        float4 v = ((const float4*)x)[i];
        bf16x4v o; o[0]=(bf16)v.x; o[1]=(bf16)v.y; o[2]=(bf16)v.z; o[3]=(bf16)v.w;
        ((bf16x4v*)xb)[i] = o;
    }
    for (int i = tid; i < (3*DM*DM)/4; i += stride) {
        int n = i >> 8, k4 = i & 255;
        const float* src = (n < 1024) ? Wq : (n < 2048) ? Wk : Wv;
        float4 v = ((const float4*)(src + (size_t)(n & 1023) * DM))[k4];
        bf16x4v o; o[0]=(bf16)v.x; o[1]=(bf16)v.y; o[2]=(bf16)v.z; o[3]=(bf16)v.w;
        ((bf16x4v*)wqkvb)[i] = o;
    }
    for (int i = tid; i < (DM*DM)/4; i += stride) {
        float4 v = ((const float4*)Wo)[i];
        bf16x4v o; o[0]=(bf16)v.x; o[1]=(bf16)v.y; o[2]=(bf16)v.z; o[3]=(bf16)v.w;
        ((bf16x4v*)wob)[i] = o;
    }
    for (int i = tid; i < H_ * SEQ_; i += stride) {
        int h = i >> 10, dist = i & 1023;
        int bkt;
        if (dist < 16) {
            bkt = dist;
        } else {
            float r = logf((float)dist * (1.0f/16.0f)) / logf(8.0f) * 16.0f;
            int vb = 16 + (int)r;
            bkt = vb > 31 ? 31 : vb;
        }
        biasT[i] = rel[bkt * H_ + h] * 0.125f;
    }
}

// ---------------------------------------------------------------------------
// GEMM C = A @ B^T  (both A and B K-contiguous, bf16, fp32 accumulate)
// 128x128 tile, BK=64, 256 threads (4 waves, 2x2 of 64x64), mfma 16x16x32
// ---------------------------------------------------------------------------
template<int MODE>
__global__ __launch_bounds__(256) void gemm_bt(
    const bf16* __restrict__ A, const bf16* __restrict__ Bm, int K,
    bf16* __restrict__ qb, bf16* __restrict__ kb, bf16* __restrict__ vtb,
    const float* __restrict__ bq, const float* __restrict__ bk,
    const float* __restrict__ bv,
    float* __restrict__ outp, const float* __restrict__ bo, int Nout)
{
    __shared__ __align__(16) bf16 As[128 * 64];
    __shared__ __align__(16) bf16 Bs[128 * 64];

    int t = threadIdx.x;
    int lane = t & 63, w = t >> 6;
    int wr = w >> 1, wc = w & 1;
    int m0 = blockIdx.y * 128, n0 = blockIdx.x * 128;
    int row_l = lane & 15;
    int ksl = (lane >> 4) * 8;

    f32x4 acc[4][4] = {};

    for (int k0 = 0; k0 < K; k0 += 64) {
        #pragma unroll
        for (int i = 0; i < 4; ++i) {
            int e = i * 2048 + t * 8;
            int r = e >> 6, c = e & 63;
            gl_lds16(A  + (long)(m0 + r) * K + k0 + c, &As[i * 2048 + w * 512]);
            gl_lds16(Bm + (long)(n0 + r) * K + k0 + c, &Bs[i * 2048 + w * 512]);
        }
        __syncthreads();
        #pragma unroll
        for (int kk = 0; kk < 2; ++kk) {
            bf16x8 af[4], bfr[4];
            #pragma unroll
            for (int mi = 0; mi < 4; ++mi)
                af[mi] = *(const bf16x8*)&As[(wr*64 + mi*16 + row_l)*64 + kk*32 + ksl];
            #pragma unroll
            for (int ni = 0; ni < 4; ++ni)
                bfr[ni] = *(const bf16x8*)&Bs[(wc*64 + ni*16 + row_l)*64 + kk*32 + ksl];
            #pragma unroll
            for (int mi = 0; mi < 4; ++mi)
                #pragma unroll
                for (int ni = 0; ni < 4; ++ni)
                    acc[mi][ni] = __builtin_amdgcn_mfma_f32_16x16x32_bf16(
                        af[mi], bfr[ni], acc[mi][ni], 0, 0, 0);
        }
        __syncthreads();
    }

    int rbase = (lane >> 4) * 4;
    #pragma unroll
    for (int mi = 0; mi < 4; ++mi) {
        #pragma unroll
        for (int ni = 0; ni < 4; ++ni) {
            #pragma unroll
            for (int g = 0; g < 4; ++g) {
                int m = m0 + wr*64 + mi*16 + rbase + g;
                int n = n0 + wc*64 + ni*16 + (lane & 15);
                float v = acc[mi][ni][g];
                if (MODE == 0) {
                    int which = n >> 10, nn = n & 1023;
                    int h = nn >> 6, d = nn & 63;
                    int b = m >> 10, s = m & 1023;
                    const float* bias = (which == 0) ? bq : (which == 1) ? bk : bv;
                    v += bias[nn];
                    bf16 bv16 = (bf16)v;
                    if (which == 0)
                        qb[((long)(b*H_ + h)*SEQ_ + s)*HD + d] = bv16;
                    else if (which == 1)
                        kb[((long)(b*H_ + h)*SEQ_ + s)*HD + d] = bv16;
                    else
                        vtb[((long)(b*H_ + h)*HD + d)*SEQ_ + s] = bv16;
                } else {
                    outp[(long)m * Nout + n] = v + bo[n];
                }
            }
        }
    }
}

// ---------------------------------------------------------------------------
// Flash attention v3:
//  - grid 512, XCD-localized: each XCD owns 8 whole (b,h) groups (2MB < L2)
//  - causal pairing: block handles q-tiles {qt, 15-qt} -> 17 steps/block
//  - K/V double-buffered LDS staging via global_load_lds (pre-swizzled src)
//  - XOR-swizzled ds_read_b128 (T2), padded per-wave P buffer
// ---------------------------------------------------------------------------
#define PSTRIDE 72

__global__ __launch_bounds__(256) void attn_kernel(
    const bf16* __restrict__ Qb, const bf16* __restrict__ Kb,
    const bf16* __restrict__ Vtb, const float* __restrict__ biasT,
    bf16* __restrict__ AO)
{
    __shared__ __align__(16) bf16 Ks[2][64 * 64];
    __shared__ __align__(16) bf16 Vs[2][64 * 64];
    __shared__ __align__(16) bf16 Ps[4][16 * PSTRIDE];
    __shared__ float biasS[SEQ_];

    int t = threadIdx.x;
    int lane = t & 63, w = t >> 6;

    // XCD-localized decode: xcd = bid%8 owns groups [xcd*8, xcd*8+8)
    int bid = blockIdx.x;
    int xcd = bid & 7;
    int widx = bid >> 3;            // 0..63
    int g = xcd * 8 + (widx >> 3);  // bh group 0..63
    int pair = widx & 7;            // 0..7
    int qt_lo = pair, qt_hi = 15 - pair;
    int h = g & 15, b = g >> 4;

    int row_l = lane & 15;
    int ksl = (lane >> 4) * 8;
    int rbase = (lane >> 4) * 4;

    // bias row for this head -> LDS
    ((float4*)biasS)[t] = ((const float4*)(biasT + (long)h * SEQ_))[t];

    const bf16* Kbase = Kb + (long)g * SEQ_ * HD;
    const bf16* Vbase = Vtb + (long)g * HD * SEQ_;

    // Q fragments for both q-tiles (held in registers)
    const bf16* QpA = Qb + ((long)g * SEQ_ + qt_lo * 64 + w * 16) * HD;
    const bf16* QpB = Qb + ((long)g * SEQ_ + qt_hi * 64 + w * 16) * HD;
    bf16x8 qA0 = *(const bf16x8*)&QpA[row_l * HD + ksl];
    bf16x8 qA1 = *(const bf16x8*)&QpA[row_l * HD + 32 + ksl];
    bf16x8 qB0 = *(const bf16x8*)&QpB[row_l * HD + ksl];
    bf16x8 qB1 = *(const bf16x8*)&QpB[row_l * HD + 32 + ksl];

    f32x4 oaccA[4] = {}, oaccB[4] = {};
    float mA[4], lA[4], mB[4], lB[4];
    int irA[4], irB[4];
    #pragma unroll
    for (int q = 0; q < 4; ++q) {
        mA[q] = -1e30f; lA[q] = 0.f; mB[q] = -1e30f; lB[q] = 0.f;
        irA[q] = qt_lo * 64 + w * 16 + rbase + q;
        irB[q] = qt_hi * 64 + w * 16 + rbase + q;
    }

    // staging: pre-swizzled global source, linear LDS dest
    int srow = w * 8 + (lane >> 3);               // + i*32
    int csw  = ((lane & 7) ^ (lane >> 3)) * 8;    // swizzled 8-elem chunk

    // prologue: stage tile 0 into buf 0
    {
        int jt = 0;
        #pragma unroll
        for (int i = 0; i < 2; ++i) {
            int r = i * 32 + srow;
            gl_lds16(Kbase + (long)(jt*64 + r) * HD + csw, &Ks[0][i*2048 + w*512]);
            gl_lds16(Vbase + (long)r * SEQ_ + jt*64 + csw, &Vs[0][i*2048 + w*512]);
        }
    }
    __syncthreads();

    int cur = 0;
    for (int jt = 0; jt <= qt_hi; ++jt) {
        // stage next tile into the other buffer (overlaps with compute)
        if (jt < qt_hi) {
            int nb = cur ^ 1, jn = jt + 1;
            #pragma unroll
            for (int i = 0; i < 2; ++i) {
                int r = i * 32 + srow;
                gl_lds16(Kbase + (long)(jn*64 + r) * HD + csw, &Ks[nb][i*2048 + w*512]);
                gl_lds16(Vbase + (long)r * SEQ_ + jn*64 + csw, &Vs[nb][i*2048 + w*512]);
            }
        }
        bool dolo = (jt <= qt_lo);

        // K fragments (swizzled reads), S for both q-tiles
        f32x4 sA[4] = {}, sB[4] = {};
        #pragma unroll
        for (int f = 0; f < 4; ++f) {
            int ra = f * 16 + row_l;
            int a0 = (ra * 64 + ksl)      ^ ((ra & 7) << 3);
            int a1 = (ra * 64 + 32 + ksl) ^ ((ra & 7) << 3);
            bf16x8 kf0 = *(const bf16x8*)&Ks[cur][a0];
            bf16x8 kf1 = *(const bf16x8*)&Ks[cur][a1];
            sB[f] = __builtin_amdgcn_mfma_f32_16x16x32_bf16(qB0, kf0, sB[f], 0,0,0);
            sB[f] = __builtin_amdgcn_mfma_f32_16x16x32_bf16(qB1, kf1, sB[f], 0,0,0);
            if (dolo) {
                sA[f] = __builtin_amdgcn_mfma_f32_16x16x32_bf16(qA0, kf0, sA[f], 0,0,0);
                sA[f] = __builtin_amdgcn_mfma_f32_16x16x32_bf16(qA1, kf1, sA[f], 0,0,0);
            }
        }

        // V fragments (swizzled reads) for PV of both tiles
        bf16x8 vf[4][2];
        #pragma unroll
        for (int f = 0; f < 4; ++f) {
            int ra = f * 16 + row_l;
            int a0 = (ra * 64 + ksl)      ^ ((ra & 7) << 3);
            int a1 = (ra * 64 + 32 + ksl) ^ ((ra & 7) << 3);
            vf[f][0] = *(const bf16x8*)&Vs[cur][a0];
            vf[f][1] = *(const bf16x8*)&Vs[cur][a1];
        }

        // ---- hi tile: mask+softmax+PV
        {
            float s_v[4][4];
            #pragma unroll
            for (int f = 0; f < 4; ++f) {
                int j = jt * 64 + f * 16 + row_l;
                #pragma unroll
                for (int q = 0; q < 4; ++q)
                    s_v[f][q] = (j <= irB[q]) ? (sB[f][q] + biasS[irB[q] - j]) : -1e30f;
            }
            float pv[4][4], sc_a[4];
            #pragma unroll
            for (int q = 0; q < 4; ++q) {
                float mx = fmaxf(fmaxf(s_v[0][q], s_v[1][q]), fmaxf(s_v[2][q], s_v[3][q]));
                #pragma unroll
                for (int off = 1; off < 16; off <<= 1) mx = fmaxf(mx, __shfl_xor(mx, off));
                float mnew = fmaxf(mB[q], mx);
                float sc = __expf(mB[q] - mnew);
                float rs = 0.f;
                #pragma unroll
                for (int f = 0; f < 4; ++f) {
                    float p = __expf(s_v[f][q] - mnew);
                    pv[f][q] = p; rs += p;
                }
                #pragma unroll
                for (int off = 1; off < 16; off <<= 1) rs += __shfl_xor(rs, off);
                lB[q] = lB[q] * sc + rs; mB[q] = mnew; sc_a[q] = sc;
            }
            #pragma unroll
            for (int db = 0; db < 4; ++db)
                #pragma unroll
                for (int q = 0; q < 4; ++q)
                    oaccB[db][q] *= sc_a[q];
            #pragma unroll
            for (int f = 0; f < 4; ++f)
                #pragma unroll
                for (int q = 0; q < 4; ++q)
                    Ps[w][(rbase + q) * PSTRIDE + f * 16 + row_l] = (bf16)pv[f][q];
            bf16x8 pf0 = *(const bf16x8*)&Ps[w][row_l * PSTRIDE + ksl];
            bf16x8 pf1 = *(const bf16x8*)&Ps[w][row_l * PSTRIDE + 32 + ksl];
            #pragma unroll
            for (int db = 0; db < 4; ++db) {
                oaccB[db] = __builtin_amdgcn_mfma_f32_16x16x32_bf16(pf0, vf[db][0], oaccB[db], 0,0,0);
                oaccB[db] = __builtin_amdgcn_mfma_f32_16x16x32_bf16(pf1, vf[db][1], oaccB[db], 0,0,0);
            }
        }

        // ---- lo tile
        if (dolo) {
            float s_v[4][4];
            #pragma unroll
            for (int f = 0; f < 4; ++f) {
                int j = jt * 64 + f * 16 + row_l;
                #pragma unroll
                for (int q = 0; q < 4; ++q)
                    s_v[f][q] = (j <= irA[q]) ? (sA[f][q] + biasS[irA[q] - j]) : -1e30f;
            }
            float pv[4][4], sc_a[4];
            #pragma unroll
            for (int q = 0; q < 4; ++q) {
                float mx = fmaxf(fmaxf(s_v[0][q], s_v[1][q]), fmaxf(s_v[2][q], s_v[3][q]));
                #pragma unroll
                for (int off = 1; off < 16; off <<= 1) mx = fmaxf(mx, __shfl_xor(mx, off));
                float mnew = fmaxf(mA[q], mx);
                float sc = __expf(mA[q] - mnew);
                float rs = 0.f;
                #pragma unroll
                for (int f = 0; f < 4; ++f) {
                    float p = __expf(s_v[f][q] - mnew);
                    pv[f][q] = p; rs += p;
                }
                #pragma unroll
                for (int off = 1; off < 16; off <<= 1) rs += __shfl_xor(rs, off);
                lA[q] = lA[q] * sc + rs; mA[q] = mnew; sc_a[q] = sc;
            }
            #pragma unroll
            for (int db = 0; db < 4; ++db)
                #pragma unroll
                for (int q = 0; q < 4; ++q)
                    oaccA[db][q] *= sc_a[q];
            #pragma unroll
            for (int f = 0; f < 4; ++f)
                #pragma unroll
                for (int q = 0; q < 4; ++q)
                    Ps[w][(rbase + q) * PSTRIDE + f * 16 + row_l] = (bf16)pv[f][q];
            bf16x8 pf0 = *(const bf16x8*)&Ps[w][row_l * PSTRIDE + ksl];
            bf16x8 pf1 = *(const bf16x8*)&Ps[w][row_l * PSTRIDE + 32 + ksl];
            #pragma unroll
            for (int db = 0; db < 4; ++db) {
                oaccA[db] = __builtin_amdgcn_mfma_f32_16x16x32_bf16(pf0, vf[db][0], oaccA[db], 0,0,0);
                oaccA[db] = __builtin_amdgcn_mfma_f32_16x16x32_bf16(pf1, vf[db][1], oaccA[db], 0,0,0);
            }
        }

        __syncthreads();   // staging of next buf done + all reads of cur done
        cur ^= 1;
    }

    // epilogue: both tiles
    #pragma unroll
    for (int q = 0; q < 4; ++q) {
        float invA = 1.0f / lA[q];
        float invB = 1.0f / lB[q];
        long baseA = ((long)(b * SEQ_ + irA[q])) * DM + h * HD;
        long baseB = ((long)(b * SEQ_ + irB[q])) * DM + h * HD;
        #pragma unroll
        for (int db = 0; db < 4; ++db) {
            AO[baseA + db * 16 + row_l] = (bf16)(oaccA[db][q] * invA);
            AO[baseB + db * 16 + row_l] = (bf16)(oaccB[db][q] * invB);
        }
    }
}

// ---------------------------------------------------------------------------
extern "C" void kernel_launch(void* const* d_in, const int* in_sizes, int n_in,
                              void* d_out, int out_size, void* d_ws, size_t ws_size,
                              hipStream_t stream)
{
    const float* x   = (const float*)d_in[0];
    const float* Wq  = (const float*)d_in[1];
    const float* bq  = (const float*)d_in[2];
    const float* Wk  = (const float*)d_in[3];
    const float* bk  = (const float*)d_in[4];
    const float* Wv  = (const float*)d_in[5];
    const float* bv  = (const float*)d_in[6];
    const float* Wo  = (const float*)d_in[7];
    const float* bo  = (const float*)d_in[8];
    const float* rel = (const float*)d_in[9];
    float* out = (float*)d_out;

    char* ws = (char*)d_ws;
    bf16* xb    = (bf16*)ws;  ws += (size_t)B_*SEQ_*DM * 2;
    bf16* wqkvb = (bf16*)ws;  ws += (size_t)3*DM*DM * 2;
    bf16* wob   = (bf16*)ws;  ws += (size_t)DM*DM * 2;
    float* biasT= (float*)ws; ws += (size_t)H_*SEQ_ * 4;
    bf16* Qb    = (bf16*)ws;  ws += (size_t)B_*H_*SEQ_*HD * 2;
    bf16* Kb2   = (bf16*)ws;  ws += (size_t)B_*H_*SEQ_*HD * 2;
    bf16* Vtb   = (bf16*)ws;  ws += (size_t)B_*H_*SEQ_*HD * 2;
    bf16* AO    = (bf16*)ws;  ws += (size_t)B_*SEQ_*DM * 2;

    prep_kernel<<<2048, 256, 0, stream>>>(x, Wq, Wk, Wv, Wo, rel,
                                          xb, wqkvb, wob, biasT);

    dim3 g1(24, 32);
    gemm_bt<0><<<g1, 256, 0, stream>>>(xb, wqkvb, DM,
                                       Qb, Kb2, Vtb, bq, bk, bv,
                                       nullptr, nullptr, 0);

    attn_kernel<<<512, 256, 0, stream>>>(Qb, Kb2, Vtb, biasT, AO);

    dim3 g3(8, 32);
    gemm_bt<1><<<g3, 256, 0, stream>>>(AO, wob, DM,
                                       nullptr, nullptr, nullptr,
                                       nullptr, nullptr, nullptr,
                                       out, bo, DM);
}

// Round 4
// 142.989 us; speedup vs baseline: 1.5497x; 1.0652x over previous
//
#include <hip/hip_runtime.h>
#include <hip/hip_bf16.h>
#include <stdint.h>

#define B_   4
#define SEQ_ 1024
#define DM   1024
#define H_   16
#define HD   64

typedef __bf16 bf16;
typedef __bf16 bf16x8 __attribute__((ext_vector_type(8)));
typedef __bf16 bf16x4v __attribute__((ext_vector_type(4)));
typedef float  f32x4 __attribute__((ext_vector_type(4)));

__device__ __forceinline__ void gl_lds16(const void* g, void* s_uniform) {
    __builtin_amdgcn_global_load_lds(
        (const __attribute__((address_space(1))) uint32_t*)g,
        (__attribute__((address_space(3))) uint32_t*)s_uniform,
        16, 0, 0);
}

// ---------------------------------------------------------------------------
// prep: fp32 -> bf16 casts + T5 relative-position bias table [h][dist]
// ---------------------------------------------------------------------------
__global__ __launch_bounds__(256) void prep_kernel(
    const float* __restrict__ x, const float* __restrict__ Wq,
    const float* __restrict__ Wk, const float* __restrict__ Wv,
    const float* __restrict__ Wo, const float* __restrict__ rel,
    bf16* __restrict__ xb, bf16* __restrict__ wqkvb, bf16* __restrict__ wob,
    float* __restrict__ biasT)
{
    int tid = blockIdx.x * 256 + threadIdx.x;
    int stride = gridDim.x * 256;

    for (int i = tid; i < (B_*SEQ_*DM)/4; i += stride) {
        float4 v = ((const float4*)x)[i];
        bf16x4v o; o[0]=(bf16)v.x; o[1]=(bf16)v.y; o[2]=(bf16)v.z; o[3]=(bf16)v.w;
        ((bf16x4v*)xb)[i] = o;
    }
    for (int i = tid; i < (3*DM*DM)/4; i += stride) {
        int n = i >> 8, k4 = i & 255;
        const float* src = (n < 1024) ? Wq : (n < 2048) ? Wk : Wv;
        float4 v = ((const float4*)(src + (size_t)(n & 1023) * DM))[k4];
        bf16x4v o; o[0]=(bf16)v.x; o[1]=(bf16)v.y; o[2]=(bf16)v.z; o[3]=(bf16)v.w;
        ((bf16x4v*)wqkvb)[i] = o;
    }
    for (int i = tid; i < (DM*DM)/4; i += stride) {
        float4 v = ((const float4*)Wo)[i];
        bf16x4v o; o[0]=(bf16)v.x; o[1]=(bf16)v.y; o[2]=(bf16)v.z; o[3]=(bf16)v.w;
        ((bf16x4v*)wob)[i] = o;
    }
    for (int i = tid; i < H_ * SEQ_; i += stride) {
        int h = i >> 10, dist = i & 1023;
        int bkt;
        if (dist < 16) {
            bkt = dist;
        } else {
            float r = logf((float)dist * (1.0f/16.0f)) / logf(8.0f) * 16.0f;
            int vb = 16 + (int)r;
            bkt = vb > 31 ? 31 : vb;
        }
        biasT[i] = rel[bkt * H_ + h] * 0.125f;
    }
}

// ---------------------------------------------------------------------------
// 2-phase double-buffered GEMM  C = A @ B^T   (T3-minimum structure)
// 512 threads = 8 waves (2M x 4N). BM = MR*32, BN = NR*64, BK = 64.
// Stage(next) issued BEFORE compute; one vmcnt(0) + one raw s_barrier / tile.
// MODE 0: QKV scatter epilogue (bias add, Q/K row-major, V transposed)
// MODE 1: fp32 C + bias epilogue
// ---------------------------------------------------------------------------
template<int MR, int NR, int MODE, int MINW>
__global__ __launch_bounds__(512, MINW) void gemm2(
    const bf16* __restrict__ Ag, const bf16* __restrict__ Bg,
    int K, int ntx, int chunk,
    bf16* __restrict__ qb, bf16* __restrict__ kb, bf16* __restrict__ vtb,
    const float* __restrict__ bq, const float* __restrict__ bk,
    const float* __restrict__ bv,
    float* __restrict__ outp, const float* __restrict__ bo, int Nout)
{
    constexpr int BM = MR * 32;
    constexpr int BN = NR * 64;
    constexpr int NISS = (BM + BN) / 64;   // gl_lds issues per thread per K-tile

    __shared__ __align__(16) bf16 tile[2][(BM + BN) * 64];

    const int t = threadIdx.x;
    const int lane = t & 63, w = t >> 6;
    const int wr = w >> 2, wc = w & 3;
    const int row_l = lane & 15;
    const int ksl = (lane >> 4) * 8;

    // T1: bijective XCD-chunked swizzle (nwg = 8*chunk guaranteed)
    int sw = (blockIdx.x & 7) * chunk + (blockIdx.x >> 3);
    int tx = sw % ntx, ty = sw / ntx;
    const int m0 = ty * BM, n0 = tx * BN;

    f32x4 acc[MR][NR] = {};

    auto STAGE = [&](int buf, int kt) {
        #pragma unroll
        for (int i = 0; i < NISS; ++i) {
            int e = i * 4096 + t * 8;
            int r = e >> 6, c = e & 63;
            const bf16* src = (r < BM)
                ? (Ag + (long)(m0 + r) * K + kt * 64 + c)
                : (Bg + (long)(n0 + r - BM) * K + kt * 64 + c);
            gl_lds16(src, &tile[buf][i * 4096 + w * 512]);
        }
    };

    const int NT = K >> 6;

    STAGE(0, 0);
    asm volatile("s_waitcnt vmcnt(0)" ::: "memory");
    __builtin_amdgcn_s_barrier();

    int cur = 0;
    for (int kt = 0; kt < NT; ++kt) {
        if (kt + 1 < NT) STAGE(cur ^ 1, kt + 1);

        #pragma unroll
        for (int ks = 0; ks < 2; ++ks) {
            bf16x8 af[MR], bfr[NR];
            #pragma unroll
            for (int m = 0; m < MR; ++m)
                af[m] = *(const bf16x8*)&tile[cur][(wr*(BM/2) + m*16 + row_l)*64 + ks*32 + ksl];
            #pragma unroll
            for (int n = 0; n < NR; ++n)
                bfr[n] = *(const bf16x8*)&tile[cur][(BM + wc*(NR*16) + n*16 + row_l)*64 + ks*32 + ksl];
            #pragma unroll
            for (int m = 0; m < MR; ++m)
                #pragma unroll
                for (int n = 0; n < NR; ++n)
                    acc[m][n] = __builtin_amdgcn_mfma_f32_16x16x32_bf16(
                        af[m], bfr[n], acc[m][n], 0, 0, 0);
        }

        asm volatile("s_waitcnt vmcnt(0)" ::: "memory");
        __builtin_amdgcn_s_barrier();
        cur ^= 1;
    }

    const int rbase = (lane >> 4) * 4;
    #pragma unroll
    for (int m = 0; m < MR; ++m) {
        #pragma unroll
        for (int n = 0; n < NR; ++n) {
            #pragma unroll
            for (int g = 0; g < 4; ++g) {
                int gm = m0 + wr*(BM/2) + m*16 + rbase + g;
                int gn = n0 + wc*(NR*16) + n*16 + row_l;
                float v = acc[m][n][g];
                if (MODE == 0) {
                    int which = gn >> 10, nn = gn & 1023;
                    int h = nn >> 6, d = nn & 63;
                    int b = gm >> 10, s = gm & 1023;
                    const float* bias = (which == 0) ? bq : (which == 1) ? bk : bv;
                    v += bias[nn];
                    bf16 bv16 = (bf16)v;
                    if (which == 0)
                        qb[((long)(b*H_ + h)*SEQ_ + s)*HD + d] = bv16;
                    else if (which == 1)
                        kb[((long)(b*H_ + h)*SEQ_ + s)*HD + d] = bv16;
                    else
                        vtb[((long)(b*H_ + h)*HD + d)*SEQ_ + s] = bv16;
                } else {
                    outp[(long)gm * Nout + gn] = v + bo[gn];
                }
            }
        }
    }
}

// ---------------------------------------------------------------------------
// Flash attention v3 (unchanged from round 3):
//  - grid 512, XCD-localized groups; causal pairing {qt, 15-qt}
//  - K/V double-buffered LDS via global_load_lds (pre-swizzled src)
//  - XOR-swizzled ds_read_b128, padded per-wave P buffer
// ---------------------------------------------------------------------------
#define PSTRIDE 72

__global__ __launch_bounds__(256) void attn_kernel(
    const bf16* __restrict__ Qb, const bf16* __restrict__ Kb,
    const bf16* __restrict__ Vtb, const float* __restrict__ biasT,
    bf16* __restrict__ AO)
{
    __shared__ __align__(16) bf16 Ks[2][64 * 64];
    __shared__ __align__(16) bf16 Vs[2][64 * 64];
    __shared__ __align__(16) bf16 Ps[4][16 * PSTRIDE];
    __shared__ float biasS[SEQ_];

    int t = threadIdx.x;
    int lane = t & 63, w = t >> 6;

    int bid = blockIdx.x;
    int xcd = bid & 7;
    int widx = bid >> 3;
    int g = xcd * 8 + (widx >> 3);
    int pair = widx & 7;
    int qt_lo = pair, qt_hi = 15 - pair;
    int h = g & 15, b = g >> 4;

    int row_l = lane & 15;
    int ksl = (lane >> 4) * 8;
    int rbase = (lane >> 4) * 4;

    ((float4*)biasS)[t] = ((const float4*)(biasT + (long)h * SEQ_))[t];

    const bf16* Kbase = Kb + (long)g * SEQ_ * HD;
    const bf16* Vbase = Vtb + (long)g * HD * SEQ_;

    const bf16* QpA = Qb + ((long)g * SEQ_ + qt_lo * 64 + w * 16) * HD;
    const bf16* QpB = Qb + ((long)g * SEQ_ + qt_hi * 64 + w * 16) * HD;
    bf16x8 qA0 = *(const bf16x8*)&QpA[row_l * HD + ksl];
    bf16x8 qA1 = *(const bf16x8*)&QpA[row_l * HD + 32 + ksl];
    bf16x8 qB0 = *(const bf16x8*)&QpB[row_l * HD + ksl];
    bf16x8 qB1 = *(const bf16x8*)&QpB[row_l * HD + 32 + ksl];

    f32x4 oaccA[4] = {}, oaccB[4] = {};
    float mA[4], lA[4], mB[4], lB[4];
    int irA[4], irB[4];
    #pragma unroll
    for (int q = 0; q < 4; ++q) {
        mA[q] = -1e30f; lA[q] = 0.f; mB[q] = -1e30f; lB[q] = 0.f;
        irA[q] = qt_lo * 64 + w * 16 + rbase + q;
        irB[q] = qt_hi * 64 + w * 16 + rbase + q;
    }

    int srow = w * 8 + (lane >> 3);
    int csw  = ((lane & 7) ^ (lane >> 3)) * 8;

    {
        int jt = 0;
        #pragma unroll
        for (int i = 0; i < 2; ++i) {
            int r = i * 32 + srow;
            gl_lds16(Kbase + (long)(jt*64 + r) * HD + csw, &Ks[0][i*2048 + w*512]);
            gl_lds16(Vbase + (long)r * SEQ_ + jt*64 + csw, &Vs[0][i*2048 + w*512]);
        }
    }
    __syncthreads();

    int cur = 0;
    for (int jt = 0; jt <= qt_hi; ++jt) {
        if (jt < qt_hi) {
            int nb = cur ^ 1, jn = jt + 1;
            #pragma unroll
            for (int i = 0; i < 2; ++i) {
                int r = i * 32 + srow;
                gl_lds16(Kbase + (long)(jn*64 + r) * HD + csw, &Ks[nb][i*2048 + w*512]);
                gl_lds16(Vbase + (long)r * SEQ_ + jn*64 + csw, &Vs[nb][i*2048 + w*512]);
            }
        }
        bool dolo = (jt <= qt_lo);

        f32x4 sA[4] = {}, sB[4] = {};
        #pragma unroll
        for (int f = 0; f < 4; ++f) {
            int ra = f * 16 + row_l;
            int a0 = (ra * 64 + ksl)      ^ ((ra & 7) << 3);
            int a1 = (ra * 64 + 32 + ksl) ^ ((ra & 7) << 3);
            bf16x8 kf0 = *(const bf16x8*)&Ks[cur][a0];
            bf16x8 kf1 = *(const bf16x8*)&Ks[cur][a1];
            sB[f] = __builtin_amdgcn_mfma_f32_16x16x32_bf16(qB0, kf0, sB[f], 0,0,0);
            sB[f] = __builtin_amdgcn_mfma_f32_16x16x32_bf16(qB1, kf1, sB[f], 0,0,0);
            if (dolo) {
                sA[f] = __builtin_amdgcn_mfma_f32_16x16x32_bf16(qA0, kf0, sA[f], 0,0,0);
                sA[f] = __builtin_amdgcn_mfma_f32_16x16x32_bf16(qA1, kf1, sA[f], 0,0,0);
            }
        }

        bf16x8 vf[4][2];
        #pragma unroll
        for (int f = 0; f < 4; ++f) {
            int ra = f * 16 + row_l;
            int a0 = (ra * 64 + ksl)      ^ ((ra & 7) << 3);
            int a1 = (ra * 64 + 32 + ksl) ^ ((ra & 7) << 3);
            vf[f][0] = *(const bf16x8*)&Vs[cur][a0];
            vf[f][1] = *(const bf16x8*)&Vs[cur][a1];
        }

        {
            float s_v[4][4];
            #pragma unroll
            for (int f = 0; f < 4; ++f) {
                int j = jt * 64 + f * 16 + row_l;
                #pragma unroll
                for (int q = 0; q < 4; ++q)
                    s_v[f][q] = (j <= irB[q]) ? (sB[f][q] + biasS[irB[q] - j]) : -1e30f;
            }
            float pv[4][4], sc_a[4];
            #pragma unroll
            for (int q = 0; q < 4; ++q) {
                float mx = fmaxf(fmaxf(s_v[0][q], s_v[1][q]), fmaxf(s_v[2][q], s_v[3][q]));
                #pragma unroll
                for (int off = 1; off < 16; off <<= 1) mx = fmaxf(mx, __shfl_xor(mx, off));
                float mnew = fmaxf(mB[q], mx);
                float sc = __expf(mB[q] - mnew);
                float rs = 0.f;
                #pragma unroll
                for (int f = 0; f < 4; ++f) {
                    float p = __expf(s_v[f][q] - mnew);
                    pv[f][q] = p; rs += p;
                }
                #pragma unroll
                for (int off = 1; off < 16; off <<= 1) rs += __shfl_xor(rs, off);
                lB[q] = lB[q] * sc + rs; mB[q] = mnew; sc_a[q] = sc;
            }
            #pragma unroll
            for (int db = 0; db < 4; ++db)
                #pragma unroll
                for (int q = 0; q < 4; ++q)
                    oaccB[db][q] *= sc_a[q];
            #pragma unroll
            for (int f = 0; f < 4; ++f)
                #pragma unroll
                for (int q = 0; q < 4; ++q)
                    Ps[w][(rbase + q) * PSTRIDE + f * 16 + row_l] = (bf16)pv[f][q];
            bf16x8 pf0 = *(const bf16x8*)&Ps[w][row_l * PSTRIDE + ksl];
            bf16x8 pf1 = *(const bf16x8*)&Ps[w][row_l * PSTRIDE + 32 + ksl];
            #pragma unroll
            for (int db = 0; db < 4; ++db) {
                oaccB[db] = __builtin_amdgcn_mfma_f32_16x16x32_bf16(pf0, vf[db][0], oaccB[db], 0,0,0);
                oaccB[db] = __builtin_amdgcn_mfma_f32_16x16x32_bf16(pf1, vf[db][1], oaccB[db], 0,0,0);
            }
        }

        if (dolo) {
            float s_v[4][4];
            #pragma unroll
            for (int f = 0; f < 4; ++f) {
                int j = jt * 64 + f * 16 + row_l;
                #pragma unroll
                for (int q = 0; q < 4; ++q)
                    s_v[f][q] = (j <= irA[q]) ? (sA[f][q] + biasS[irA[q] - j]) : -1e30f;
            }
            float pv[4][4], sc_a[4];
            #pragma unroll
            for (int q = 0; q < 4; ++q) {
                float mx = fmaxf(fmaxf(s_v[0][q], s_v[1][q]), fmaxf(s_v[2][q], s_v[3][q]));
                #pragma unroll
                for (int off = 1; off < 16; off <<= 1) mx = fmaxf(mx, __shfl_xor(mx, off));
                float mnew = fmaxf(mA[q], mx);
                float sc = __expf(mA[q] - mnew);
                float rs = 0.f;
                #pragma unroll
                for (int f = 0; f < 4; ++f) {
                    float p = __expf(s_v[f][q] - mnew);
                    pv[f][q] = p; rs += p;
                }
                #pragma unroll
                for (int off = 1; off < 16; off <<= 1) rs += __shfl_xor(rs, off);
                lA[q] = lA[q] * sc + rs; mA[q] = mnew; sc_a[q] = sc;
            }
            #pragma unroll
            for (int db = 0; db < 4; ++db)
                #pragma unroll
                for (int q = 0; q < 4; ++q)
                    oaccA[db][q] *= sc_a[q];
            #pragma unroll
            for (int f = 0; f < 4; ++f)
                #pragma unroll
                for (int q = 0; q < 4; ++q)
                    Ps[w][(rbase + q) * PSTRIDE + f * 16 + row_l] = (bf16)pv[f][q];
            bf16x8 pf0 = *(const bf16x8*)&Ps[w][row_l * PSTRIDE + ksl];
            bf16x8 pf1 = *(const bf16x8*)&Ps[w][row_l * PSTRIDE + 32 + ksl];
            #pragma unroll
            for (int db = 0; db < 4; ++db) {
                oaccA[db] = __builtin_amdgcn_mfma_f32_16x16x32_bf16(pf0, vf[db][0], oaccA[db], 0,0,0);
                oaccA[db] = __builtin_amdgcn_mfma_f32_16x16x32_bf16(pf1, vf[db][1], oaccA[db], 0,0,0);
            }
        }

        __syncthreads();
        cur ^= 1;
    }

    #pragma unroll
    for (int q = 0; q < 4; ++q) {
        float invA = 1.0f / lA[q];
        float invB = 1.0f / lB[q];
        long baseA = ((long)(b * SEQ_ + irA[q])) * DM + h * HD;
        long baseB = ((long)(b * SEQ_ + irB[q])) * DM + h * HD;
        #pragma unroll
        for (int db = 0; db < 4; ++db) {
            AO[baseA + db * 16 + row_l] = (bf16)(oaccA[db][q] * invA);
            AO[baseB + db * 16 + row_l] = (bf16)(oaccB[db][q] * invB);
        }
    }
}

// ---------------------------------------------------------------------------
extern "C" void kernel_launch(void* const* d_in, const int* in_sizes, int n_in,
                              void* d_out, int out_size, void* d_ws, size_t ws_size,
                              hipStream_t stream)
{
    const float* x   = (const float*)d_in[0];
    const float* Wq  = (const float*)d_in[1];
    const float* bq  = (const float*)d_in[2];
    const float* Wk  = (const float*)d_in[3];
    const float* bk  = (const float*)d_in[4];
    const float* Wv  = (const float*)d_in[5];
    const float* bv  = (const float*)d_in[6];
    const float* Wo  = (const float*)d_in[7];
    const float* bo  = (const float*)d_in[8];
    const float* rel = (const float*)d_in[9];
    float* out = (float*)d_out;

    char* ws = (char*)d_ws;
    bf16* xb    = (bf16*)ws;  ws += (size_t)B_*SEQ_*DM * 2;
    bf16* wqkvb = (bf16*)ws;  ws += (size_t)3*DM*DM * 2;
    bf16* wob   = (bf16*)ws;  ws += (size_t)DM*DM * 2;
    float* biasT= (float*)ws; ws += (size_t)H_*SEQ_ * 4;
    bf16* Qb    = (bf16*)ws;  ws += (size_t)B_*H_*SEQ_*HD * 2;
    bf16* Kb2   = (bf16*)ws;  ws += (size_t)B_*H_*SEQ_*HD * 2;
    bf16* Vtb   = (bf16*)ws;  ws += (size_t)B_*H_*SEQ_*HD * 2;
    bf16* AO    = (bf16*)ws;  ws += (size_t)B_*SEQ_*DM * 2;

    prep_kernel<<<2048, 256, 0, stream>>>(x, Wq, Wk, Wv, Wo, rel,
                                          xb, wqkvb, wob, biasT);

    // QKV: M=4096, N=3072 -> 16 x 12 = 192 blocks of 256x256
    gemm2<8, 4, 0, 2><<<192, 512, 0, stream>>>(
        xb, wqkvb, DM, /*ntx=*/12, /*chunk=*/24,
        Qb, Kb2, Vtb, bq, bk, bv, nullptr, nullptr, 0);

    attn_kernel<<<512, 256, 0, stream>>>(Qb, Kb2, Vtb, biasT, AO);

    // out-proj: M=4096, N=1024 -> 32 x 8 = 256 blocks of 128x128
    gemm2<4, 2, 1, 4><<<256, 512, 0, stream>>>(
        AO, wob, DM, /*ntx=*/8, /*chunk=*/32,
        nullptr, nullptr, nullptr, nullptr, nullptr, nullptr,
        out, bo, DM);
}

// Round 5
// 138.493 us; speedup vs baseline: 1.6000x; 1.0325x over previous
//
#include <hip/hip_runtime.h>
#include <hip/hip_bf16.h>
#include <stdint.h>

#define B_   4
#define SEQ_ 1024
#define DM   1024
#define H_   16
#define HD   64

typedef __bf16 bf16;
typedef __bf16 bf16x8 __attribute__((ext_vector_type(8)));
typedef __bf16 bf16x4v __attribute__((ext_vector_type(4)));
typedef float  f32x4 __attribute__((ext_vector_type(4)));

__device__ __forceinline__ void gl_lds16(const void* g, void* s_uniform) {
    __builtin_amdgcn_global_load_lds(
        (const __attribute__((address_space(1))) uint32_t*)g,
        (__attribute__((address_space(3))) uint32_t*)s_uniform,
        16, 0, 0);
}

// ---------------------------------------------------------------------------
// prep: fp32 -> bf16 casts + T5 relative-position bias table [h][dist]
// ---------------------------------------------------------------------------
__global__ __launch_bounds__(256) void prep_kernel(
    const float* __restrict__ x, const float* __restrict__ Wq,
    const float* __restrict__ Wk, const float* __restrict__ Wv,
    const float* __restrict__ Wo, const float* __restrict__ rel,
    bf16* __restrict__ xb, bf16* __restrict__ wqkvb, bf16* __restrict__ wob,
    float* __restrict__ biasT)
{
    int tid = blockIdx.x * 256 + threadIdx.x;
    int stride = gridDim.x * 256;

    for (int i = tid; i < (B_*SEQ_*DM)/4; i += stride) {
        float4 v = ((const float4*)x)[i];
        bf16x4v o; o[0]=(bf16)v.x; o[1]=(bf16)v.y; o[2]=(bf16)v.z; o[3]=(bf16)v.w;
        ((bf16x4v*)xb)[i] = o;
    }
    for (int i = tid; i < (3*DM*DM)/4; i += stride) {
        int n = i >> 8, k4 = i & 255;
        const float* src = (n < 1024) ? Wq : (n < 2048) ? Wk : Wv;
        float4 v = ((const float4*)(src + (size_t)(n & 1023) * DM))[k4];
        bf16x4v o; o[0]=(bf16)v.x; o[1]=(bf16)v.y; o[2]=(bf16)v.z; o[3]=(bf16)v.w;
        ((bf16x4v*)wqkvb)[i] = o;
    }
    for (int i = tid; i < (DM*DM)/4; i += stride) {
        float4 v = ((const float4*)Wo)[i];
        bf16x4v o; o[0]=(bf16)v.x; o[1]=(bf16)v.y; o[2]=(bf16)v.z; o[3]=(bf16)v.w;
        ((bf16x4v*)wob)[i] = o;
    }
    for (int i = tid; i < H_ * SEQ_; i += stride) {
        int h = i >> 10, dist = i & 1023;
        int bkt;
        if (dist < 16) {
            bkt = dist;
        } else {
            float r = logf((float)dist * (1.0f/16.0f)) / logf(8.0f) * 16.0f;
            int vb = 16 + (int)r;
            bkt = vb > 31 ? 31 : vb;
        }
        biasT[i] = rel[bkt * H_ + h] * 0.125f;
    }
}

// ---------------------------------------------------------------------------
// Ring-pipelined GEMM (QKV): C = A @ B^T, BM=BN=256, BK=32, 512 thr (8 waves
// 2Mx4N), 4 LDS buffers, prefetch depth 3, counted vmcnt (never 0 in loop),
// XOR-swizzled LDS (pre-swizzled global source + swizzled ds_read).
// Epilogue: bias add + scatter Q(b,h,s,d), K(b,h,s,d), Vt(b,h,d,s) bf16.
// ---------------------------------------------------------------------------
template<int NT>
__global__ __launch_bounds__(512, 2) void gemm_ring(
    const bf16* __restrict__ Ag, const bf16* __restrict__ Bg,
    int ntx, int chunk,
    bf16* __restrict__ qb, bf16* __restrict__ kb, bf16* __restrict__ vtb,
    const float* __restrict__ bq, const float* __restrict__ bk,
    const float* __restrict__ bv)
{
    constexpr int BM = 256, BN = 256, BK = 32;
    __shared__ __align__(16) bf16 tile[4][(BM + BN) * BK];   // 4 x 32 KB

    const int t = threadIdx.x;
    const int lane = t & 63, w = t >> 6;
    const int wr = w >> 2, wc = w & 3;
    const int row_l = lane & 15;
    const int q = lane >> 4;           // k-chunk 0..3 (8 elems each)

    // T1: bijective XCD-chunked swizzle (grid = 8*chunk)
    int sw = (blockIdx.x & 7) * chunk + (blockIdx.x >> 3);
    int tx = sw % ntx, ty = sw / ntx;
    const int m0 = ty * BM, n0 = tx * BN;

    f32x4 acc[8][4] = {};

    auto STAGE = [&](int kt) {
        bf16* dst = &tile[kt & 3][0];
        #pragma unroll
        for (int i = 0; i < 4; ++i) {
            int e = i * 4096 + t * 8;          // elem in 512x32 staging space
            int r = e >> 5;                    // staging row 0..511
            int cc = (e >> 3) & 3;             // chunk 0..3
            int csw = (cc ^ (r & 3)) << 3;     // pre-swizzled source column
            const bf16* src = (r < BM)
                ? (Ag + (long)(m0 + r) * DM + kt * BK + csw)
                : (Bg + (long)(n0 + r - BM) * DM + kt * BK + csw);
            gl_lds16(src, dst + i * 4096 + w * 512);   // wave-uniform dest
        }
    };

    auto COMPUTE = [&](int kt) {
        const bf16* buf = &tile[kt & 3][0];
        bf16x8 af[8], bfr[4];
        #pragma unroll
        for (int m = 0; m < 8; ++m) {
            int ra = wr * 128 + m * 16 + row_l;
            af[m] = *(const bf16x8*)&buf[ra * 32 + ((q ^ (ra & 3)) << 3)];
        }
        #pragma unroll
        for (int n = 0; n < 4; ++n) {
            int rb = wc * 64 + n * 16 + row_l;
            bfr[n] = *(const bf16x8*)&buf[BM * 32 + rb * 32 + ((q ^ (rb & 3)) << 3)];
        }
        #pragma unroll
        for (int m = 0; m < 8; ++m)
            #pragma unroll
            for (int n = 0; n < 4; ++n)
                acc[m][n] = __builtin_amdgcn_mfma_f32_16x16x32_bf16(
                    af[m], bfr[n], acc[m][n], 0, 0, 0);
    };

    // prologue: prefetch 3 tiles deep
    STAGE(0); STAGE(1); STAGE(2);

    for (int kt = 0; kt < NT - 3; ++kt) {
        asm volatile("s_waitcnt vmcnt(8)" ::: "memory");  // oldest tile ready
        __builtin_amdgcn_s_barrier();
        STAGE(kt + 3);                                     // into buf[(kt-1)&3]
        COMPUTE(kt);
    }
    asm volatile("s_waitcnt vmcnt(8)" ::: "memory");
    __builtin_amdgcn_s_barrier();
    COMPUTE(NT - 3);
    asm volatile("s_waitcnt vmcnt(4)" ::: "memory");
    __builtin_amdgcn_s_barrier();
    COMPUTE(NT - 2);
    asm volatile("s_waitcnt vmcnt(0)" ::: "memory");
    __builtin_amdgcn_s_barrier();
    COMPUTE(NT - 1);

    // epilogue: bias + QKV scatter
    const int rbase = (lane >> 4) * 4;
    #pragma unroll
    for (int m = 0; m < 8; ++m) {
        #pragma unroll
        for (int n = 0; n < 4; ++n) {
            #pragma unroll
            for (int g = 0; g < 4; ++g) {
                int gm = m0 + wr * 128 + m * 16 + rbase + g;
                int gn = n0 + wc * 64 + n * 16 + row_l;
                float v = acc[m][n][g];
                int which = gn >> 10, nn = gn & 1023;
                int h = nn >> 6, d = nn & 63;
                int b = gm >> 10, s = gm & 1023;
                const float* bias = (which == 0) ? bq : (which == 1) ? bk : bv;
                v += bias[nn];
                bf16 bv16 = (bf16)v;
                if (which == 0)
                    qb[((long)(b*H_ + h)*SEQ_ + s)*HD + d] = bv16;
                else if (which == 1)
                    kb[((long)(b*H_ + h)*SEQ_ + s)*HD + d] = bv16;
                else
                    vtb[((long)(b*H_ + h)*HD + d)*SEQ_ + s] = bv16;
            }
        }
    }
}

// ---------------------------------------------------------------------------
// 2-phase double-buffered GEMM (out-proj): C = A @ B^T + bias, fp32 out.
// 512 threads = 8 waves (2M x 4N). BM = MR*32, BN = NR*64, BK = 64.
// ---------------------------------------------------------------------------
template<int MR, int NR, int MINW>
__global__ __launch_bounds__(512, MINW) void gemm2(
    const bf16* __restrict__ Ag, const bf16* __restrict__ Bg,
    int K, int ntx, int chunk,
    float* __restrict__ outp, const float* __restrict__ bo, int Nout)
{
    constexpr int BM = MR * 32;
    constexpr int BN = NR * 64;
    constexpr int NISS = (BM + BN) / 64;

    __shared__ __align__(16) bf16 tile[2][(BM + BN) * 64];

    const int t = threadIdx.x;
    const int lane = t & 63, w = t >> 6;
    const int wr = w >> 2, wc = w & 3;
    const int row_l = lane & 15;
    const int ksl = (lane >> 4) * 8;

    int sw = (blockIdx.x & 7) * chunk + (blockIdx.x >> 3);
    int tx = sw % ntx, ty = sw / ntx;
    const int m0 = ty * BM, n0 = tx * BN;

    f32x4 acc[MR][NR] = {};

    auto STAGE = [&](int buf, int kt) {
        #pragma unroll
        for (int i = 0; i < NISS; ++i) {
            int e = i * 4096 + t * 8;
            int r = e >> 6, c = e & 63;
            const bf16* src = (r < BM)
                ? (Ag + (long)(m0 + r) * K + kt * 64 + c)
                : (Bg + (long)(n0 + r - BM) * K + kt * 64 + c);
            gl_lds16(src, &tile[buf][i * 4096 + w * 512]);
        }
    };

    const int NT = K >> 6;

    STAGE(0, 0);
    asm volatile("s_waitcnt vmcnt(0)" ::: "memory");
    __builtin_amdgcn_s_barrier();

    int cur = 0;
    for (int kt = 0; kt < NT; ++kt) {
        if (kt + 1 < NT) STAGE(cur ^ 1, kt + 1);

        #pragma unroll
        for (int ks = 0; ks < 2; ++ks) {
            bf16x8 af[MR], bfr[NR];
            #pragma unroll
            for (int m = 0; m < MR; ++m)
                af[m] = *(const bf16x8*)&tile[cur][(wr*(BM/2) + m*16 + row_l)*64 + ks*32 + ksl];
            #pragma unroll
            for (int n = 0; n < NR; ++n)
                bfr[n] = *(const bf16x8*)&tile[cur][(BM + wc*(NR*16) + n*16 + row_l)*64 + ks*32 + ksl];
            #pragma unroll
            for (int m = 0; m < MR; ++m)
                #pragma unroll
                for (int n = 0; n < NR; ++n)
                    acc[m][n] = __builtin_amdgcn_mfma_f32_16x16x32_bf16(
                        af[m], bfr[n], acc[m][n], 0, 0, 0);
        }

        asm volatile("s_waitcnt vmcnt(0)" ::: "memory");
        __builtin_amdgcn_s_barrier();
        cur ^= 1;
    }

    const int rbase = (lane >> 4) * 4;
    #pragma unroll
    for (int m = 0; m < MR; ++m) {
        #pragma unroll
        for (int n = 0; n < NR; ++n) {
            #pragma unroll
            for (int g = 0; g < 4; ++g) {
                int gm = m0 + wr*(BM/2) + m*16 + rbase + g;
                int gn = n0 + wc*(NR*16) + n*16 + row_l;
                outp[(long)gm * Nout + gn] = acc[m][n][g] + bo[gn];
            }
        }
    }
}

// ---------------------------------------------------------------------------
// Flash attention (unchanged from round 3/4)
// ---------------------------------------------------------------------------
#define PSTRIDE 72

__global__ __launch_bounds__(256) void attn_kernel(
    const bf16* __restrict__ Qb, const bf16* __restrict__ Kb,
    const bf16* __restrict__ Vtb, const float* __restrict__ biasT,
    bf16* __restrict__ AO)
{
    __shared__ __align__(16) bf16 Ks[2][64 * 64];
    __shared__ __align__(16) bf16 Vs[2][64 * 64];
    __shared__ __align__(16) bf16 Ps[4][16 * PSTRIDE];
    __shared__ float biasS[SEQ_];

    int t = threadIdx.x;
    int lane = t & 63, w = t >> 6;

    int bid = blockIdx.x;
    int xcd = bid & 7;
    int widx = bid >> 3;
    int g = xcd * 8 + (widx >> 3);
    int pair = widx & 7;
    int qt_lo = pair, qt_hi = 15 - pair;
    int h = g & 15, b = g >> 4;

    int row_l = lane & 15;
    int ksl = (lane >> 4) * 8;
    int rbase = (lane >> 4) * 4;

    ((float4*)biasS)[t] = ((const float4*)(biasT + (long)h * SEQ_))[t];

    const bf16* Kbase = Kb + (long)g * SEQ_ * HD;
    const bf16* Vbase = Vtb + (long)g * HD * SEQ_;

    const bf16* QpA = Qb + ((long)g * SEQ_ + qt_lo * 64 + w * 16) * HD;
    const bf16* QpB = Qb + ((long)g * SEQ_ + qt_hi * 64 + w * 16) * HD;
    bf16x8 qA0 = *(const bf16x8*)&QpA[row_l * HD + ksl];
    bf16x8 qA1 = *(const bf16x8*)&QpA[row_l * HD + 32 + ksl];
    bf16x8 qB0 = *(const bf16x8*)&QpB[row_l * HD + ksl];
    bf16x8 qB1 = *(const bf16x8*)&QpB[row_l * HD + 32 + ksl];

    f32x4 oaccA[4] = {}, oaccB[4] = {};
    float mA[4], lA[4], mB[4], lB[4];
    int irA[4], irB[4];
    #pragma unroll
    for (int q = 0; q < 4; ++q) {
        mA[q] = -1e30f; lA[q] = 0.f; mB[q] = -1e30f; lB[q] = 0.f;
        irA[q] = qt_lo * 64 + w * 16 + rbase + q;
        irB[q] = qt_hi * 64 + w * 16 + rbase + q;
    }

    int srow = w * 8 + (lane >> 3);
    int csw  = ((lane & 7) ^ (lane >> 3)) * 8;

    {
        int jt = 0;
        #pragma unroll
        for (int i = 0; i < 2; ++i) {
            int r = i * 32 + srow;
            gl_lds16(Kbase + (long)(jt*64 + r) * HD + csw, &Ks[0][i*2048 + w*512]);
            gl_lds16(Vbase + (long)r * SEQ_ + jt*64 + csw, &Vs[0][i*2048 + w*512]);
        }
    }
    __syncthreads();

    int cur = 0;
    for (int jt = 0; jt <= qt_hi; ++jt) {
        if (jt < qt_hi) {
            int nb = cur ^ 1, jn = jt + 1;
            #pragma unroll
            for (int i = 0; i < 2; ++i) {
                int r = i * 32 + srow;
                gl_lds16(Kbase + (long)(jn*64 + r) * HD + csw, &Ks[nb][i*2048 + w*512]);
                gl_lds16(Vbase + (long)r * SEQ_ + jn*64 + csw, &Vs[nb][i*2048 + w*512]);
            }
        }
        bool dolo = (jt <= qt_lo);

        f32x4 sA[4] = {}, sB[4] = {};
        #pragma unroll
        for (int f = 0; f < 4; ++f) {
            int ra = f * 16 + row_l;
            int a0 = (ra * 64 + ksl)      ^ ((ra & 7) << 3);
            int a1 = (ra * 64 + 32 + ksl) ^ ((ra & 7) << 3);
            bf16x8 kf0 = *(const bf16x8*)&Ks[cur][a0];
            bf16x8 kf1 = *(const bf16x8*)&Ks[cur][a1];
            sB[f] = __builtin_amdgcn_mfma_f32_16x16x32_bf16(qB0, kf0, sB[f], 0,0,0);
            sB[f] = __builtin_amdgcn_mfma_f32_16x16x32_bf16(qB1, kf1, sB[f], 0,0,0);
            if (dolo) {
                sA[f] = __builtin_amdgcn_mfma_f32_16x16x32_bf16(qA0, kf0, sA[f], 0,0,0);
                sA[f] = __builtin_amdgcn_mfma_f32_16x16x32_bf16(qA1, kf1, sA[f], 0,0,0);
            }
        }

        bf16x8 vf[4][2];
        #pragma unroll
        for (int f = 0; f < 4; ++f) {
            int ra = f * 16 + row_l;
            int a0 = (ra * 64 + ksl)      ^ ((ra & 7) << 3);
            int a1 = (ra * 64 + 32 + ksl) ^ ((ra & 7) << 3);
            vf[f][0] = *(const bf16x8*)&Vs[cur][a0];
            vf[f][1] = *(const bf16x8*)&Vs[cur][a1];
        }

        {
            float s_v[4][4];
            #pragma unroll
            for (int f = 0; f < 4; ++f) {
                int j = jt * 64 + f * 16 + row_l;
                #pragma unroll
                for (int q = 0; q < 4; ++q)
                    s_v[f][q] = (j <= irB[q]) ? (sB[f][q] + biasS[irB[q] - j]) : -1e30f;
            }
            float pv[4][4], sc_a[4];
            #pragma unroll
            for (int q = 0; q < 4; ++q) {
                float mx = fmaxf(fmaxf(s_v[0][q], s_v[1][q]), fmaxf(s_v[2][q], s_v[3][q]));
                #pragma unroll
                for (int off = 1; off < 16; off <<= 1) mx = fmaxf(mx, __shfl_xor(mx, off));
                float mnew = fmaxf(mB[q], mx);
                float sc = __expf(mB[q] - mnew);
                float rs = 0.f;
                #pragma unroll
                for (int f = 0; f < 4; ++f) {
                    float p = __expf(s_v[f][q] - mnew);
                    pv[f][q] = p; rs += p;
                }
                #pragma unroll
                for (int off = 1; off < 16; off <<= 1) rs += __shfl_xor(rs, off);
                lB[q] = lB[q] * sc + rs; mB[q] = mnew; sc_a[q] = sc;
            }
            #pragma unroll
            for (int db = 0; db < 4; ++db)
                #pragma unroll
                for (int q = 0; q < 4; ++q)
                    oaccB[db][q] *= sc_a[q];
            #pragma unroll
            for (int f = 0; f < 4; ++f)
                #pragma unroll
                for (int q = 0; q < 4; ++q)
                    Ps[w][(rbase + q) * PSTRIDE + f * 16 + row_l] = (bf16)pv[f][q];
            bf16x8 pf0 = *(const bf16x8*)&Ps[w][row_l * PSTRIDE + ksl];
            bf16x8 pf1 = *(const bf16x8*)&Ps[w][row_l * PSTRIDE + 32 + ksl];
            #pragma unroll
            for (int db = 0; db < 4; ++db) {
                oaccB[db] = __builtin_amdgcn_mfma_f32_16x16x32_bf16(pf0, vf[db][0], oaccB[db], 0,0,0);
                oaccB[db] = __builtin_amdgcn_mfma_f32_16x16x32_bf16(pf1, vf[db][1], oaccB[db], 0,0,0);
            }
        }

        if (dolo) {
            float s_v[4][4];
            #pragma unroll
            for (int f = 0; f < 4; ++f) {
                int j = jt * 64 + f * 16 + row_l;
                #pragma unroll
                for (int q = 0; q < 4; ++q)
                    s_v[f][q] = (j <= irA[q]) ? (sA[f][q] + biasS[irA[q] - j]) : -1e30f;
            }
            float pv[4][4], sc_a[4];
            #pragma unroll
            for (int q = 0; q < 4; ++q) {
                float mx = fmaxf(fmaxf(s_v[0][q], s_v[1][q]), fmaxf(s_v[2][q], s_v[3][q]));
                #pragma unroll
                for (int off = 1; off < 16; off <<= 1) mx = fmaxf(mx, __shfl_xor(mx, off));
                float mnew = fmaxf(mA[q], mx);
                float sc = __expf(mA[q] - mnew);
                float rs = 0.f;
                #pragma unroll
                for (int f = 0; f < 4; ++f) {
                    float p = __expf(s_v[f][q] - mnew);
                    pv[f][q] = p; rs += p;
                }
                #pragma unroll
                for (int off = 1; off < 16; off <<= 1) rs += __shfl_xor(rs, off);
                lA[q] = lA[q] * sc + rs; mA[q] = mnew; sc_a[q] = sc;
            }
            #pragma unroll
            for (int db = 0; db < 4; ++db)
                #pragma unroll
                for (int q = 0; q < 4; ++q)
                    oaccA[db][q] *= sc_a[q];
            #pragma unroll
            for (int f = 0; f < 4; ++f)
                #pragma unroll
                for (int q = 0; q < 4; ++q)
                    Ps[w][(rbase + q) * PSTRIDE + f * 16 + row_l] = (bf16)pv[f][q];
            bf16x8 pf0 = *(const bf16x8*)&Ps[w][row_l * PSTRIDE + ksl];
            bf16x8 pf1 = *(const bf16x8*)&Ps[w][row_l * PSTRIDE + 32 + ksl];
            #pragma unroll
            for (int db = 0; db < 4; ++db) {
                oaccA[db] = __builtin_amdgcn_mfma_f32_16x16x32_bf16(pf0, vf[db][0], oaccA[db], 0,0,0);
                oaccA[db] = __builtin_amdgcn_mfma_f32_16x16x32_bf16(pf1, vf[db][1], oaccA[db], 0,0,0);
            }
        }

        __syncthreads();
        cur ^= 1;
    }

    #pragma unroll
    for (int q = 0; q < 4; ++q) {
        float invA = 1.0f / lA[q];
        float invB = 1.0f / lB[q];
        long baseA = ((long)(b * SEQ_ + irA[q])) * DM + h * HD;
        long baseB = ((long)(b * SEQ_ + irB[q])) * DM + h * HD;
        #pragma unroll
        for (int db = 0; db < 4; ++db) {
            AO[baseA + db * 16 + row_l] = (bf16)(oaccA[db][q] * invA);
            AO[baseB + db * 16 + row_l] = (bf16)(oaccB[db][q] * invB);
        }
    }
}

// ---------------------------------------------------------------------------
extern "C" void kernel_launch(void* const* d_in, const int* in_sizes, int n_in,
                              void* d_out, int out_size, void* d_ws, size_t ws_size,
                              hipStream_t stream)
{
    const float* x   = (const float*)d_in[0];
    const float* Wq  = (const float*)d_in[1];
    const float* bq  = (const float*)d_in[2];
    const float* Wk  = (const float*)d_in[3];
    const float* bk  = (const float*)d_in[4];
    const float* Wv  = (const float*)d_in[5];
    const float* bv  = (const float*)d_in[6];
    const float* Wo  = (const float*)d_in[7];
    const float* bo  = (const float*)d_in[8];
    const float* rel = (const float*)d_in[9];
    float* out = (float*)d_out;

    char* ws = (char*)d_ws;
    bf16* xb    = (bf16*)ws;  ws += (size_t)B_*SEQ_*DM * 2;
    bf16* wqkvb = (bf16*)ws;  ws += (size_t)3*DM*DM * 2;
    bf16* wob   = (bf16*)ws;  ws += (size_t)DM*DM * 2;
    float* biasT= (float*)ws; ws += (size_t)H_*SEQ_ * 4;
    bf16* Qb    = (bf16*)ws;  ws += (size_t)B_*H_*SEQ_*HD * 2;
    bf16* Kb2   = (bf16*)ws;  ws += (size_t)B_*H_*SEQ_*HD * 2;
    bf16* Vtb   = (bf16*)ws;  ws += (size_t)B_*H_*SEQ_*HD * 2;
    bf16* AO    = (bf16*)ws;  ws += (size_t)B_*SEQ_*DM * 2;

    prep_kernel<<<2048, 256, 0, stream>>>(x, Wq, Wk, Wv, Wo, rel,
                                          xb, wqkvb, wob, biasT);

    // QKV: M=4096, N=3072 -> 16 x 12 = 192 blocks of 256x256, K=1024 -> NT=32
    gemm_ring<32><<<192, 512, 0, stream>>>(
        xb, wqkvb, /*ntx=*/12, /*chunk=*/24,
        Qb, Kb2, Vtb, bq, bk, bv);

    attn_kernel<<<512, 256, 0, stream>>>(Qb, Kb2, Vtb, biasT, AO);

    // out-proj: M=4096, N=1024 -> 32 x 8 = 256 blocks of 128x128
    gemm2<4, 2, 4><<<256, 512, 0, stream>>>(
        AO, wob, DM, /*ntx=*/8, /*chunk=*/32,
        out, bo, DM);
}